// Round 5
// baseline (259.141 us; speedup 1.0000x reference)
//
#include <hip/hip_runtime.h>
#include <hip/hip_bf16.h>
#include <hip/hip_fp16.h>
#include <math.h>

#define ICH   3
#define OCH   16
#define ID    18
#define IH    34
#define IW    34
#define OD    16
#define OH    32
#define OW    32
#define NB    128
#define PLANE_W  36                 // padded row stride in halfs (8B-aligned rows)
#define PLANE_SZ (PLANE_W * IH)     // 1224 halfs per plane
#define NPLANES  (ICH * 4)          // 3 ic x 4 d-slices
#define SPATIAL  (OD * OH * OW)     // 16384 per (b,c)
#define EPSV     1e-5f

__device__ __forceinline__ unsigned short f2bf(float f) {
    unsigned int u = __float_as_uint(f);
    unsigned int r = (u + 0x7fffu + ((u >> 16) & 1u)) >> 16;
    return (unsigned short)r;
}

// Grid: 128 b x 8 dchunk = 1024 blocks, 256 threads (exactly 4/CU -> 1 round).
// R1 compute structure (in-thread dz loop of 2, all 16 oc unrolled, 4 w/thread)
// -- proven fastest per-block. Input tile staged as fp16: LDS 59.4 -> 29.9 KB,
// so occupancy cap moves from LDS (2 blocks/CU) to VGPR (~88 -> 4 blocks/CU).
// NOTE: keep __launch_bounds__(256,2): (256,4)/(256,5) force VGPR 64/48 and
// spill to scratch (R2/R3: WRITE_SIZE +40..850 MB, up to 12x slower).
__global__ __launch_bounds__(256, 2) void conv_stats_kernel(
    const float* __restrict__ x, const float* __restrict__ cw,
    const float* __restrict__ cb, const float* __restrict__ mult,
    unsigned short* __restrict__ y, float* __restrict__ stats)
{
    __shared__ _Float16 sx[NPLANES][PLANE_SZ];   // 12 x 1224 x 2B = 29376 B
    __shared__ float wsum[4][OCH], wsq[4][OCH];

    const int blk = blockIdx.x;
    const int b  = blk >> 3;
    const int d0 = (blk & 7) * 2;
    const int tid = threadIdx.x;

    // ---- stage 12 planes x 34 rows x 34 cols: float2 gmem load -> half2 LDS ----
    for (int i = tid; i < NPLANES * IH * 17; i += 256) {
        const int row   = i / 17;              // magic-mul
        const int col2  = (i - row * 17) * 2;
        const int plane = row / IH;            // magic-mul
        const int prow  = row - plane * IH;
        const int ic = plane >> 2, dzp = plane & 3;
        const float2 v = *(const float2*)&x[
            ((size_t)(b * ICH + ic) * ID + (d0 + dzp)) * (IH * IW)
            + (size_t)prow * IW + col2];
        union { _Float16 h[2]; unsigned int u; } pk;
        pk.h[0] = (_Float16)v.x; pk.h[1] = (_Float16)v.y;
        *(unsigned int*)&sx[plane][prow * PLANE_W + col2] = pk.u;
    }
    __syncthreads();

    const int h  = tid >> 3;        // 0..31
    const int wq = (tid & 7) << 2;  // 0,4,...,28

    float ssum[OCH], ssq[OCH];
#pragma unroll
    for (int c = 0; c < OCH; c++) { ssum[c] = 0.0f; ssq[c] = 0.0f; }

    for (int dz = 0; dz < 2; dz++) {
        float acc[OCH][4];
#pragma unroll
        for (int c = 0; c < OCH; c++) {
            const float bv = cb[c];
            acc[c][0] = bv; acc[c][1] = bv; acc[c][2] = bv; acc[c][3] = bv;
        }

#pragma unroll
        for (int ic = 0; ic < ICH; ic++) {
#pragma unroll
            for (int kd = 0; kd < 3; kd++) {
                const _Float16* pl = &sx[ic * 4 + dz + kd][0];
#pragma unroll
                for (int kh = 0; kh < 3; kh++) {
                    const _Float16* row = pl + (h + kh) * PLANE_W + wq;
                    // 6 halfs, 8B-aligned: b64 + b32
                    union { unsigned int u; _Float16 h[2]; } p0, p1, p2;
                    p0.u = *(const unsigned int*)(row);
                    p1.u = *(const unsigned int*)(row + 2);
                    p2.u = *(const unsigned int*)(row + 4);
                    float in[6];
                    in[0] = (float)p0.h[0]; in[1] = (float)p0.h[1];
                    in[2] = (float)p1.h[0]; in[3] = (float)p1.h[1];
                    in[4] = (float)p2.h[0]; in[5] = (float)p2.h[1];
                    const int wbase = ic * 27 + kd * 9 + kh * 3;
#pragma unroll
                    for (int kw = 0; kw < 3; kw++) {
#pragma unroll
                        for (int c = 0; c < OCH; c++) {
                            const float wv = cw[c * 81 + wbase + kw];  // compile-time -> s_load
                            acc[c][0] = fmaf(in[kw + 0], wv, acc[c][0]);
                            acc[c][1] = fmaf(in[kw + 1], wv, acc[c][1]);
                            acc[c][2] = fmaf(in[kw + 2], wv, acc[c][2]);
                            acc[c][3] = fmaf(in[kw + 3], wv, acc[c][3]);
                        }
                    }
                }
            }
        }

        // ---- multiplier fold, stats, bf16 store ----
        const int d = d0 + dz;
#pragma unroll
        for (int c = 0; c < OCH; c++) {
            const float m = mult[c];
            const float o0 = acc[c][0] * m, o1 = acc[c][1] * m;
            const float o2 = acc[c][2] * m, o3 = acc[c][3] * m;
            ssum[c] += (o0 + o1) + (o2 + o3);
            ssq[c]  += (o0 * o0 + o1 * o1) + (o2 * o2 + o3 * o3);
            const size_t yi = ((size_t)(b * OCH + c) * OD + d) * (OH * OW)
                              + (size_t)h * OW + wq;
            ushort4 pk;
            pk.x = f2bf(o0); pk.y = f2bf(o1); pk.z = f2bf(o2); pk.w = f2bf(o3);
            *(ushort4*)&y[yi] = pk;
        }
    }

    // ---- block reduction of stats, one atomicAdd per (b,c) ----
#pragma unroll
    for (int c = 0; c < OCH; c++) {
        for (int off = 32; off > 0; off >>= 1) {
            ssum[c] += __shfl_down(ssum[c], off);
            ssq[c]  += __shfl_down(ssq[c], off);
        }
    }
    const int wave = tid >> 6, lane = tid & 63;
    if (lane == 0) {
#pragma unroll
        for (int c = 0; c < OCH; c++) { wsum[wave][c] = ssum[c]; wsq[wave][c] = ssq[c]; }
    }
    __syncthreads();
    if (tid < OCH) {
        float s = 0.0f, q = 0.0f;
#pragma unroll
        for (int k = 0; k < 4; k++) { s += wsum[k][tid]; q += wsq[k][tid]; }
        atomicAdd(&stats[(b * OCH + tid) * 2 + 0], s);
        atomicAdd(&stats[(b * OCH + tid) * 2 + 1], q);
    }
}

// Grid: 128 b x 8 segments = 1024 blocks. Each thread: 8 consecutive positions
// (one 16B load per channel), 16 channels. (R3 evidence: ~11 us, near floor.)
__global__ __launch_bounds__(256) void norm_max_kernel(
    const unsigned short* __restrict__ y, const float* __restrict__ stats,
    const float* __restrict__ mult, float* __restrict__ out)
{
    const int blk = blockIdx.x;
    const int b   = blk >> 3;
    const int seg = blk & 7;
    const int tid = threadIdx.x;

    __shared__ float srs[OCH], snb[OCH], smul[OCH];
    if (tid < OCH) {
        const float s  = stats[(b * OCH + tid) * 2 + 0];
        const float sq = stats[(b * OCH + tid) * 2 + 1];
        const float mean = s * (1.0f / (float)SPATIAL);
        float var = sq * (1.0f / (float)SPATIAL) - mean * mean;
        var = fmaxf(var, 0.0f);
        const float rs = rsqrtf(var + EPSV);
        srs[tid]  = rs;
        snb[tid]  = -mean * rs;       // normalized = v*rs + nb
        smul[tid] = mult[tid];
    }
    __syncthreads();

    const size_t ybase = (size_t)b * OCH * SPATIAL;
    const int s = seg * 2048 + tid * 8;

    float best[8];
#pragma unroll
    for (int j = 0; j < 8; j++) best[j] = -INFINITY;

#pragma unroll
    for (int c = 0; c < OCH; c++) {
        const uint4 v = *(const uint4*)&y[ybase + (size_t)c * SPATIAL + s];
        const float rs = srs[c], nb = snb[c], m = smul[c];
        const unsigned int u[4] = {v.x, v.y, v.z, v.w};
#pragma unroll
        for (int p = 0; p < 4; p++) {
            float f0 = __uint_as_float(u[p] << 16)          * rs + nb;
            float f1 = __uint_as_float(u[p] & 0xffff0000u)  * rs + nb;
            f0 = fminf(fmaxf(f0, -1.0f), 1.0f) * m;
            f1 = fminf(fmaxf(f1, -1.0f), 1.0f) * m;
            best[2 * p + 0] = fmaxf(best[2 * p + 0], f0);
            best[2 * p + 1] = fmaxf(best[2 * p + 1], f1);
        }
    }

    float* op = &out[(size_t)b * SPATIAL + s];
    float4 o0; o0.x = best[0]; o0.y = best[1]; o0.z = best[2]; o0.w = best[3];
    float4 o1; o1.x = best[4]; o1.y = best[5]; o1.z = best[6]; o1.w = best[7];
    *(float4*)op = o0;
    *(float4*)(op + 4) = o1;
}

extern "C" void kernel_launch(void* const* d_in, const int* in_sizes, int n_in,
                              void* d_out, int out_size, void* d_ws, size_t ws_size,
                              hipStream_t stream) {
    const float* x    = (const float*)d_in[0];
    const float* cw   = (const float*)d_in[1];
    const float* cb   = (const float*)d_in[2];
    const float* mult = (const float*)d_in[3];
    float* out = (float*)d_out;

    unsigned short* y = (unsigned short*)d_ws;
    float* stats = (float*)((char*)d_ws + (size_t)NB * OCH * SPATIAL * sizeof(unsigned short));

    hipMemsetAsync(stats, 0, (size_t)NB * OCH * 2 * sizeof(float), stream);
    conv_stats_kernel<<<NB * 8, 256, 0, stream>>>(x, cw, cb, mult, y, stats);
    norm_max_kernel<<<NB * 8, 256, 0, stream>>>(y, stats, mult, out);
}

// Round 6
// 176.072 us; speedup vs baseline: 1.4718x; 1.4718x over previous
//
#include <hip/hip_runtime.h>
#include <hip/hip_bf16.h>
#include <math.h>

#define ICH   3
#define OCH   16
#define ID    18
#define IH    34
#define IW    34
#define OD    16
#define OH    32
#define OW    32
#define NB    128
#define PLANE_W  36                 // padded row stride (aligned float4 at w%4==0)
#define PLANE_SZ (PLANE_W * IH)     // 36*34 = 1224 floats per plane
#define DCHUNK   2
#define IN_D     (DCHUNK + 2)       // 4 input d-planes per chunk
#define SPATIAL  (OD * OH * OW)     // 16384 per (b,c)
#define EPSV     1e-5f

__device__ __forceinline__ unsigned short f2bf(float f) {
    unsigned int u = __float_as_uint(f);
    unsigned int r = (u + 0x7fffu + ((u >> 16) & 1u)) >> 16;
    return (unsigned short)r;
}

// ===== conv: byte-exact R1 structure (proven 108 us; every deviation since
// regressed). 1024 blocks, 59.4 KB LDS, fp32 staging, in-thread dz reuse,
// all-16-oc unroll w/ compile-time weight idx (s_load path), VGPR 88 no spill.
// Do NOT: raise min-waves (forces spill), fp16/bf16 staging (cvt VALU +
// scratch), split dz across waves (2x staging per output).
__global__ __launch_bounds__(256, 2) void conv_stats_kernel(
    const float* __restrict__ x, const float* __restrict__ cw,
    const float* __restrict__ cb, const float* __restrict__ mult,
    unsigned short* __restrict__ y, float* __restrict__ stats)
{
    __shared__ float sx[ICH][IN_D][PLANE_SZ];
    __shared__ float wsum[4][OCH], wsq[4][OCH];

    const int blk = blockIdx.x;
    const int b = blk >> 3;
    const int d0 = (blk & 7) * DCHUNK;
    const int tid = threadIdx.x;

    for (int idx = tid; idx < ICH * IN_D * IH * IW; idx += 256) {
        int t = idx;
        const int wcol = t % IW; t /= IW;
        const int hrow = t % IH; t /= IH;
        const int dz = t % IN_D; t /= IN_D;
        const int ic = t;
        sx[ic][dz][hrow * PLANE_W + wcol] =
            x[(((size_t)(b * ICH + ic) * ID) + (d0 + dz)) * (IH * IW) + hrow * IW + wcol];
    }
    __syncthreads();

    const int h  = tid >> 3;        // 0..31
    const int wq = (tid & 7) << 2;  // 0,4,...,28

    float ssum[OCH], ssq[OCH];
#pragma unroll
    for (int c = 0; c < OCH; c++) { ssum[c] = 0.0f; ssq[c] = 0.0f; }

    for (int dz = 0; dz < DCHUNK; dz++) {
        float acc[OCH][4];
#pragma unroll
        for (int c = 0; c < OCH; c++) {
            const float bv = cb[c];
            acc[c][0] = bv; acc[c][1] = bv; acc[c][2] = bv; acc[c][3] = bv;
        }

        for (int ic = 0; ic < ICH; ic++) {
            for (int kd = 0; kd < 3; kd++) {
#pragma unroll
                for (int kh = 0; kh < 3; kh++) {
                    const float* row = &sx[ic][dz + kd][(h + kh) * PLANE_W + wq];
                    const float4 v0 = *(const float4*)row;
                    const float2 v1 = *(const float2*)(row + 4);
                    float in[6];
                    in[0] = v0.x; in[1] = v0.y; in[2] = v0.z; in[3] = v0.w;
                    in[4] = v1.x; in[5] = v1.y;
                    const float* wrow = &cw[(size_t)(ic * 3 + kd) * 9 + kh * 3];
#pragma unroll
                    for (int kw = 0; kw < 3; kw++) {
#pragma unroll
                        for (int c = 0; c < OCH; c++) {
                            const float wv = wrow[(size_t)c * (ICH * 27) + kw];
                            acc[c][0] = fmaf(in[kw + 0], wv, acc[c][0]);
                            acc[c][1] = fmaf(in[kw + 1], wv, acc[c][1]);
                            acc[c][2] = fmaf(in[kw + 2], wv, acc[c][2]);
                            acc[c][3] = fmaf(in[kw + 3], wv, acc[c][3]);
                        }
                    }
                }
            }
        }

        const int d = d0 + dz;
#pragma unroll
        for (int c = 0; c < OCH; c++) {
            const float m = mult[c];
            const float o0 = acc[c][0] * m, o1 = acc[c][1] * m;
            const float o2 = acc[c][2] * m, o3 = acc[c][3] * m;
            ssum[c] += (o0 + o1) + (o2 + o3);
            ssq[c]  += (o0 * o0 + o1 * o1) + (o2 * o2 + o3 * o3);
            const size_t yi = ((size_t)(b * OCH + c) * OD + d) * (OH * OW) + h * OW + wq;
            ushort4 pk;
            pk.x = f2bf(o0); pk.y = f2bf(o1); pk.z = f2bf(o2); pk.w = f2bf(o3);
            *(ushort4*)&y[yi] = pk;
        }
    }

#pragma unroll
    for (int c = 0; c < OCH; c++) {
        for (int off = 32; off > 0; off >>= 1) {
            ssum[c] += __shfl_down(ssum[c], off);
            ssq[c]  += __shfl_down(ssq[c], off);
        }
    }
    const int wave = tid >> 6, lane = tid & 63;
    if (lane == 0) {
#pragma unroll
        for (int c = 0; c < OCH; c++) { wsum[wave][c] = ssum[c]; wsq[wave][c] = ssq[c]; }
    }
    __syncthreads();
    if (tid < OCH) {
        float s = 0.0f, q = 0.0f;
#pragma unroll
        for (int k = 0; k < 4; k++) { s += wsum[k][tid]; q += wsq[k][tid]; }
        atomicAdd(&stats[(b * OCH + tid) * 2 + 0], s);
        atomicAdd(&stats[(b * OCH + tid) * 2 + 1], q);
    }
}

// ===== norm_max v3: latency-oriented rebuild. Previous versions were
// ~60 us (6x over the 11 us memory floor): 16 strided loads per thread were
// consumed semi-serially at ~900 cyc HBM latency with only 4 waves/SIMD.
// Now: 2048 blocks (8/CU -> 32 waves/CU), 4 positions/thread, ALL 16 channel
// loads (uint2, 8 B) hoisted into registers before any use;
// __launch_bounds__(256,2) gives the register budget to keep them in flight.
__global__ __launch_bounds__(256, 2) void norm_max_kernel(
    const unsigned short* __restrict__ y, const float* __restrict__ stats,
    const float* __restrict__ mult, float* __restrict__ out)
{
    const int blk = blockIdx.x;
    const int b   = blk >> 4;
    const int seg = blk & 15;
    const int tid = threadIdx.x;

    __shared__ float srs_s[OCH], snb_s[OCH], smul_s[OCH];
    if (tid < OCH) {
        const float s  = stats[(b * OCH + tid) * 2 + 0];
        const float sq = stats[(b * OCH + tid) * 2 + 1];
        const float mean = s * (1.0f / (float)SPATIAL);
        float var = sq * (1.0f / (float)SPATIAL) - mean * mean;
        var = fmaxf(var, 0.0f);
        const float rs = rsqrtf(var + EPSV);
        srs_s[tid]  = rs;
        snb_s[tid]  = -mean * rs;      // normalized = v*rs + nb
        smul_s[tid] = mult[tid];
    }
    __syncthreads();

    const int s = seg * 1024 + tid * 4;
    const unsigned short* yb = y + (size_t)b * OCH * SPATIAL + s;

    // 1) issue all 16 loads back-to-back (independent -> 16 vmem in flight)
    uint2 v[OCH];
#pragma unroll
    for (int c = 0; c < OCH; c++) {
        v[c] = *(const uint2*)(yb + (size_t)c * SPATIAL);
    }

    // 2) hoist scale/bias into registers (lgkm done before vmcnt waits start)
    float rs[OCH], nb[OCH], mm[OCH];
#pragma unroll
    for (int c = 0; c < OCH; c++) { rs[c] = srs_s[c]; nb[c] = snb_s[c]; mm[c] = smul_s[c]; }

    // 3) consume
    float b0 = -INFINITY, b1 = -INFINITY, b2 = -INFINITY, b3 = -INFINITY;
#pragma unroll
    for (int c = 0; c < OCH; c++) {
        float f0 = __uint_as_float(v[c].x << 16)         * rs[c] + nb[c];
        float f1 = __uint_as_float(v[c].x & 0xffff0000u) * rs[c] + nb[c];
        float f2 = __uint_as_float(v[c].y << 16)         * rs[c] + nb[c];
        float f3 = __uint_as_float(v[c].y & 0xffff0000u) * rs[c] + nb[c];
        f0 = fminf(fmaxf(f0, -1.0f), 1.0f) * mm[c];
        f1 = fminf(fmaxf(f1, -1.0f), 1.0f) * mm[c];
        f2 = fminf(fmaxf(f2, -1.0f), 1.0f) * mm[c];
        f3 = fminf(fmaxf(f3, -1.0f), 1.0f) * mm[c];
        b0 = fmaxf(b0, f0); b1 = fmaxf(b1, f1);
        b2 = fmaxf(b2, f2); b3 = fmaxf(b3, f3);
    }
    float4 o; o.x = b0; o.y = b1; o.z = b2; o.w = b3;
    *(float4*)&out[(size_t)b * SPATIAL + s] = o;
}

extern "C" void kernel_launch(void* const* d_in, const int* in_sizes, int n_in,
                              void* d_out, int out_size, void* d_ws, size_t ws_size,
                              hipStream_t stream) {
    const float* x    = (const float*)d_in[0];
    const float* cw   = (const float*)d_in[1];
    const float* cb   = (const float*)d_in[2];
    const float* mult = (const float*)d_in[3];
    float* out = (float*)d_out;

    unsigned short* y = (unsigned short*)d_ws;
    float* stats = (float*)((char*)d_ws + (size_t)NB * OCH * SPATIAL * sizeof(unsigned short));

    hipMemsetAsync(stats, 0, (size_t)NB * OCH * 2 * sizeof(float), stream);
    conv_stats_kernel<<<NB * 8, 256, 0, stream>>>(x, cw, cb, mult, y, stats);
    norm_max_kernel<<<NB * 16, 256, 0, stream>>>(y, stats, mult, out);
}